// Round 8
// baseline (144.841 us; speedup 1.0000x reference)
//
#include <hip/hip_runtime.h>

#define PBLOCK 256        // pair_lvl block (unchanged structure)
#define FBLOCK 128        // final kernel block = 2 waves
#define FT 512            // output elements per tile (final kernel)
#define TPB 8             // R20: tiles per block, double-buffered pipeline

typedef float v2f __attribute__((ext_vector_type(2)));

static __device__ __forceinline__ float ldz(const float* __restrict__ p, int i, int n) {
    return (i >= 0 && i < n) ? p[i] : 0.f;
}

// Phase barrier WITHOUT vmcnt drain: keeps next-tile global_load_lds +
// epilogue loads in flight across phases A..D.
#define BAR_LGKM() do { \
    asm volatile("s_waitcnt lgkmcnt(0)" ::: "memory"); \
    __builtin_amdgcn_s_barrier(); \
} while (0)

#define AS1C(p) ((const __attribute__((address_space(1))) unsigned int*)(p))
#define AS3(p)  ((__attribute__((address_space(3))) unsigned int*)(p))

// ---- scalar filter set (pair_lvl only) ----
struct QFilt {
    float b0e[5], b0o[5], a0e[5], a0o[5];
    float b1e[5], b1o[5], a1e[5], a1o[5];
};

static __device__ __forceinline__ QFilt load_qfilt(
    const float* __restrict__ g0a, const float* __restrict__ g0b,
    const float* __restrict__ g1a, const float* __restrict__ g1b) {
    const float S2 = 1.4142135623730951f;
    QFilt f;
#pragma unroll
    for (int i = 0; i < 5; ++i) {
        f.b0e[i] = g0b[8 - 2 * i]; f.b0o[i] = g0b[9 - 2 * i];
        f.a0e[i] = g0a[8 - 2 * i]; f.a0o[i] = g0a[9 - 2 * i];
        f.b1e[i] = S2 * g1b[8 - 2 * i]; f.b1o[i] = S2 * g1b[9 - 2 * i];
        f.a1e[i] = S2 * g1a[8 - 2 * i]; f.a1o[i] = S2 * g1a[9 - 2 * i];
    }
    return f;
}

// ---- packed filter set (final kernel) ----
struct QFiltP {
    v2f f01l[5], f23l[5], f01h[5], f23h[5];
};

static __device__ __forceinline__ QFiltP load_qfiltp(
    const float* __restrict__ g0a, const float* __restrict__ g0b,
    const float* __restrict__ g1a, const float* __restrict__ g1b) {
    const float S2 = 1.4142135623730951f;
    QFiltP f;
#pragma unroll
    for (int i = 0; i < 5; ++i) {
        float b0e = g0b[8 - 2 * i], b0o = g0b[9 - 2 * i];
        float a0e = g0a[8 - 2 * i], a0o = g0a[9 - 2 * i];
        float b1e = S2 * g1b[8 - 2 * i], b1o = S2 * g1b[9 - 2 * i];
        float a1e = S2 * g1a[8 - 2 * i], a1o = S2 * g1a[9 - 2 * i];
        f.f01l[i] = (v2f){b0e, a0e};
        f.f23l[i] = (v2f){b0o, a0o};
        f.f01h[i] = (v2f){b1e, a1e};
        f.f23h[i] = (v2f){b1o, a1o};
    }
    return f;
}

// Packed quad: out[4s..4s+3]. lo window as float2 loads (ds_read_b64),
// r/i pair as two b32 (mergeable to ds_read2_b32, ioff<=255).
static __device__ __forceinline__ float4 quad_p(
    const float* base, int loOff, int riOff, int ioff, const QFiltP& f) {
    v2f y01 = (v2f){0.f, 0.f}, y23 = (v2f){0.f, 0.f};
#pragma unroll
    for (int i = 0; i < 5; ++i) {
        v2f lo2 = *reinterpret_cast<const v2f*>(base + loOff + 2 * i);
        v2f ri;
        ri.x = base[riOff + i];
        ri.y = base[riOff + ioff + i];
        y01 = __builtin_elementwise_fma(lo2, f.f01l[i], y01);
        y23 = __builtin_elementwise_fma(lo2, f.f23l[i], y23);
        y01 = __builtin_elementwise_fma(ri, f.f01h[i], y01);
        y23 = __builtin_elementwise_fma(ri, f.f23h[i], y23);
    }
    return make_float4(y01.x, y01.y, y23.x, y23.y);
}

// Interleaved-window quad (pair_lvl only, unchanged).
static __device__ __forceinline__ float4 quad_i(
    const float* __restrict__ lo_s, int lobase,
    const float* __restrict__ r_s, const float* __restrict__ i_s, int ribase,
    const QFilt& f) {
    float y0 = 0.f, y1 = 0.f, y2 = 0.f, y3 = 0.f;
#pragma unroll
    for (int i = 0; i < 5; ++i) {
        float ve = lo_s[lobase + 2 * i], vo = lo_s[lobase + 2 * i + 1];
        float vr = r_s[ribase + i], vi = i_s[ribase + i];
        y0 = fmaf(ve, f.b0e[i], y0); y2 = fmaf(ve, f.b0o[i], y2);
        y1 = fmaf(vo, f.a0e[i], y1); y3 = fmaf(vo, f.a0o[i], y3);
        y0 = fmaf(vr, f.b1e[i], y0); y2 = fmaf(vr, f.b1o[i], y2);
        y1 = fmaf(vi, f.a1e[i], y1); y3 = fmaf(vi, f.a1o[i], y3);
    }
    return make_float4(y0, y1, y2, y3);
}

static __device__ __forceinline__ float4 quad_d(
    const float* __restrict__ Ae, const float* __restrict__ Ao, int base,
    const float* __restrict__ r_s, const float* __restrict__ i_s, int ribase,
    const QFilt& f) {
    float y0 = 0.f, y1 = 0.f, y2 = 0.f, y3 = 0.f;
#pragma unroll
    for (int i = 0; i < 5; ++i) {
        float ve = Ae[base + i], vo = Ao[base + i];
        float vr = r_s[ribase + i], vi = i_s[ribase + i];
        y0 = fmaf(ve, f.b0e[i], y0); y2 = fmaf(ve, f.b0o[i], y2);
        y1 = fmaf(vo, f.a0e[i], y1); y3 = fmaf(vo, f.a0o[i], y3);
        y0 = fmaf(vr, f.b1e[i], y0); y2 = fmaf(vr, f.b1o[i], y2);
        y1 = fmaf(vi, f.a1e[i], y1); y3 = fmaf(vi, f.a1o[i], y3);
    }
    return make_float4(y0, y1, y2, y3);
}

// TWO fused coarse levels (R11 structure, unchanged — measured near floor).
__global__ void __launch_bounds__(PBLOCK) pair_lvl(
    const float* __restrict__ up,
    const float* __restrict__ ru, const float* __restrict__ iu,
    const float* __restrict__ rl, const float* __restrict__ il,
    float* __restrict__ out,
    const float* __restrict__ g0a, const float* __restrict__ g0b,
    const float* __restrict__ g1a, const float* __restrict__ g1b,
    int L)
{
    __shared__ __align__(16) float upw[272], ruw[140], iuw[140], rlw[264], ilw[264];
    __shared__ __align__(16) float Ae[260], Ao[260];
    int tid = threadIdx.x, bx = blockIdx.x, row = blockIdx.y;
    int lup = L >> 2, lu8 = L >> 3, lql = L >> 2;
    const float* uprow = up + (size_t)row * lup;
    const float* rurow = ru + (size_t)row * lu8;
    const float* iurow = iu + (size_t)row * lu8;
    const float* rlrow = rl + (size_t)row * lql;
    const float* ilrow = il + (size_t)row * lql;
    bool bnd = (bx == 0) || (bx == (int)gridDim.x - 1);
    int S = bx << 8;
    int sAu = (S >> 1) - 1;
    int gu = S - 8;
    int gru = (S >> 1) - 4;
    int grl = S - 4;

    for (int i = tid; i < 270; i += PBLOCK) {
        const float* src; float* dst; int k, gb, len;
        if (i < 68)       { src = uprow; dst = upw; k = i;       gb = gu + 4 * k;  len = lup; }
        else if (i < 103) { src = rurow; dst = ruw; k = i - 68;  gb = gru + 4 * k; len = lu8; }
        else if (i < 138) { src = iurow; dst = iuw; k = i - 103; gb = gru + 4 * k; len = lu8; }
        else if (i < 204) { src = rlrow; dst = rlw; k = i - 138; gb = grl + 4 * k; len = lql; }
        else              { src = ilrow; dst = ilw; k = i - 204; gb = grl + 4 * k; len = lql; }
        float4 v;
        if (!bnd) v = *reinterpret_cast<const float4*>(src + gb);
        else { v.x = ldz(src, gb, len); v.y = ldz(src, gb + 1, len);
               v.z = ldz(src, gb + 2, len); v.w = ldz(src, gb + 3, len); }
        *reinterpret_cast<float4*>(dst + 4 * k) = v;
    }
    __syncthreads();

    QFilt f = load_qfilt(g0a, g0b, g1a, g1b);
    if (tid < 130) {
        float4 q = quad_i(upw, 2 * tid + 2, ruw, iuw, tid + 1, f);
        if (bnd) {
            int sp = sAu + tid;
            if (sp < 0 || sp >= lu8) q = make_float4(0.f, 0.f, 0.f, 0.f);
        }
        Ae[2 * tid] = q.x; Ae[2 * tid + 1] = q.z;
        Ao[2 * tid] = q.y; Ao[2 * tid + 1] = q.w;
    }
    __syncthreads();

    float4 res = quad_d(Ae, Ao, tid, rlw, ilw, tid + 2, f);
    reinterpret_cast<float4*>(out + (size_t)row * L)[S + tid] = res;
}

// ---- R20 final kernel: double-buffered persistent tiles.
// Per block: TPB=8 consecutive 512-output tiles. At each tile top, issue the
// NEXT tile's stage (global_load_lds -> other LDS buffer; zero VGPR) +
// epilogue loads (regs), then wait counted vmcnt — NEVER vmcnt(0) in steady
// state — so next-tile HBM latency hides under current tile's phases A..D.
// Wave-uniform VMEM count: stage = 2 instr/wave (wave-split slots, second
// instr exec=lanes<8 nonzero on BOTH waves), epi = 2 -> 4/wave/tile + 1 store.
// Steady-state wait: ops newer than current tile's 4 loads = store(1) +
// next prefetch(4) = vmcnt(5). First tile: vmcnt(4) (no store yet).
// LDS map (dwords): staged buffers [0,576) and [576,1152); within a buffer:
#define O_X4 0      // x4   [80]  slots   0..19
#define O_R3 80     // yh3r [40]  slots  20..29   (i3 at +40)
#define O_I3 120    // yh3i [40]  slots  30..39
#define O_R2 160    // yh2r [72]  slots  40..57   (i2 at +72)
#define O_I2 232    // yh2i [72]  slots  58..75
#define O_R1 304    // yh1r [136] slots  76..109  (i1 at +136)
#define O_I1 440    // yh1i [136] slots 110..143
#define SBUF 576    // staged-buffer stride (dwords)
#define O_X3 1152   // x3 values [144]
#define O_X2 1296   // x2 values [272]
#define O_X1 1568   // x1 quads  [520]
#define W_TOT 2088  // dwords = 8352 B
#define NSLOT 144

static __device__ __forceinline__ void slot_map(
    int i, int v0, int u0, int s0, int t4, int t8, int t16,
    const float* x4row, const float* r3row, const float* i3row,
    const float* r2row, const float* i2row,
    const float* r1row, const float* i1row,
    const float*& src, int& gb, int& len)
{
    if (i < 20)       { src = x4row; int k = i;       gb = 2 * v0 - 8 + 4 * k; len = t8;  }
    else if (i < 30)  { src = r3row; int k = i - 20;  gb = v0 - 4 + 4 * k;     len = t16; }
    else if (i < 40)  { src = i3row; int k = i - 30;  gb = v0 - 4 + 4 * k;     len = t16; }
    else if (i < 58)  { src = r2row; int k = i - 40;  gb = u0 - 4 + 4 * k;     len = t8;  }
    else if (i < 76)  { src = i2row; int k = i - 58;  gb = u0 - 4 + 4 * k;     len = t8;  }
    else if (i < 110) { src = r1row; int k = i - 76;  gb = s0 - 4 + 4 * k;     len = t4;  }
    else              { src = i1row; int k = i - 110; gb = s0 - 4 + 4 * k;     len = t4;  }
}

__global__ void __launch_bounds__(FBLOCK) final4_db(
    const float* __restrict__ x4,                                 // T/8 per row
    const float* __restrict__ r3, const float* __restrict__ i3,   // T/16 per row
    const float* __restrict__ r2, const float* __restrict__ i2,   // T/8 per row
    const float* __restrict__ r1, const float* __restrict__ i1,   // T/4 per row
    const float* __restrict__ r0, const float* __restrict__ i0,   // T/2 per row
    float* __restrict__ out,                                      // T per row
    const float* __restrict__ g0a, const float* __restrict__ g0b,
    const float* __restrict__ g1a, const float* __restrict__ g1b,
    const float* __restrict__ g0o, const float* __restrict__ g1o,
    int T_)
{
    const float S2 = 1.4142135623730951f;
    __shared__ __align__(16) float W[W_TOT];

    int row = blockIdx.y, tid = threadIdx.x, bx = blockIdx.x;
    int lane = tid & 63, wv = tid >> 6;
    int t2 = T_ >> 1, t4 = T_ >> 2, t8 = T_ >> 3, t16 = T_ >> 4;
    int NT = T_ >> 9;                       // 512 tiles of FT=512 per row
    const float* x4row = x4 + (size_t)row * t8;
    const float* r3row = r3 + (size_t)row * t16;
    const float* i3row = i3 + (size_t)row * t16;
    const float* r2row = r2 + (size_t)row * t8;
    const float* i2row = i2 + (size_t)row * t8;
    const float* r1row = r1 + (size_t)row * t4;
    const float* i1row = i1 + (size_t)row * t4;
    const float* r0row = r0 + (size_t)row * t2;
    const float* i0row = i0 + (size_t)row * t2;

    QFiltP f = load_qfiltp(g0a, g0b, g1a, g1b);
    float g0r[7], g1r[5];
#pragma unroll
    for (int j = 0; j < 7; ++j) g0r[j] = g0o[j];
#pragma unroll
    for (int j = 0; j < 5; ++j) g1r[j] = S2 * g1o[j];

    int tile0 = bx * TPB;

    // ---- async stage of tile into staged buffer at dword offset sb ----
    // Wave-split slots: wave w -> slots [72w, 72w+72); 2 VMEM instr per wave,
    // second with exec = lanes<8 (nonzero on both waves -> uniform count).
    auto stage_async = [&](int tile, int sb) {
        int v0 = tile << 5, u0 = tile << 6, s0 = tile << 7;
        {
            int slot = wv * 72 + lane;
            const float* src; int gb, len;
            slot_map(slot, v0, u0, s0, t4, t8, t16,
                     x4row, r3row, i3row, r2row, i2row, r1row, i1row, src, gb, len);
            __builtin_amdgcn_global_load_lds(AS1C(src + gb), AS3(W + sb + 4 * slot), 16, 0, 0);
        }
        if (lane < 8) {
            int slot = wv * 72 + 64 + lane;
            const float* src; int gb, len;
            slot_map(slot, v0, u0, s0, t4, t8, t16,
                     x4row, r3row, i3row, r2row, i2row, r1row, i1row, src, gb, len);
            __builtin_amdgcn_global_load_lds(AS1C(src + gb), AS3(W + sb + 4 * slot), 16, 0, 0);
        }
    };
    // Boundary-tile stage: register path with zero clamping (rare: 2 tiles).
    auto stage_reg = [&](int tile, int sb) {
        int v0 = tile << 5, u0 = tile << 6, s0 = tile << 7;
#pragma unroll
        for (int it = 0; it < 2; ++it) {
            int i = tid + FBLOCK * it;
            if (i < NSLOT) {
                const float* src; int gb, len;
                slot_map(i, v0, u0, s0, t4, t8, t16,
                         x4row, r3row, i3row, r2row, i2row, r1row, i1row, src, gb, len);
                float4 v;
                v.x = ldz(src, gb, len);     v.y = ldz(src, gb + 1, len);
                v.z = ldz(src, gb + 2, len); v.w = ldz(src, gb + 3, len);
                *reinterpret_cast<float4*>(W + sb + 4 * i) = v;
            }
        }
    };
    auto load_epi = [&](int tile, bool bnd, float4& pr, float4& pi) {
        int u0e = (tile << 8) + 2 * tid - 1;
        if (!bnd) {
            pr = *reinterpret_cast<const float4*>(r0row + u0e);
            pi = *reinterpret_cast<const float4*>(i0row + u0e);
        } else {
            pr.x = ldz(r0row, u0e, t2);     pr.y = ldz(r0row, u0e + 1, t2);
            pr.z = ldz(r0row, u0e + 2, t2); pr.w = ldz(r0row, u0e + 3, t2);
            pi.x = ldz(i0row, u0e, t2);     pi.y = ldz(i0row, u0e + 1, t2);
            pi.z = ldz(i0row, u0e + 2, t2); pi.w = ldz(i0row, u0e + 3, t2);
        }
    };

    // ---- prologue: stage tile0 into buffer 0 + its epilogue loads ----
    float4 prc, pic, prn, pin;
    {
        bool b0 = (tile0 == 0) || (tile0 == NT - 1);
        if (!b0) stage_async(tile0, 0); else stage_reg(tile0, 0);
        load_epi(tile0, b0, prc, pic);
    }

    int cur = 0;
    for (int t = 0; t < TPB; ++t) {
        int tile = tile0 + t;
        bool bndc = (tile == 0) || (tile == NT - 1);
        int s0 = tile << 7, u0 = tile << 6, v0 = tile << 5;
        int SB = cur * SBUF;

        // ---- prefetch next tile + counted-vmcnt tile barrier ----
        if (t + 1 < TPB) {
            int ntile = tile + 1;
            bool bndn = (ntile == NT - 1);        // ntile > 0 always
            if (!bndn) {
                stage_async(ntile, (cur ^ 1) * SBUF);
                load_epi(ntile, false, prn, pin);
                if (t == 0) { asm volatile("s_waitcnt vmcnt(4) lgkmcnt(0)" ::: "memory"); }
                else        { asm volatile("s_waitcnt vmcnt(5) lgkmcnt(0)" ::: "memory"); }
                __builtin_amdgcn_s_barrier();
            } else {
                stage_reg(ntile, (cur ^ 1) * SBUF);
                load_epi(ntile, true, prn, pin);
                asm volatile("s_waitcnt vmcnt(0) lgkmcnt(0)" ::: "memory");
                __builtin_amdgcn_s_barrier();
            }
        } else {
            asm volatile("s_waitcnt vmcnt(0) lgkmcnt(0)" ::: "memory");
            __builtin_amdgcn_s_barrier();
        }

        // ---- phase A: 36 x3-quads. quad v = v0-2+k. ----
        if (tid < 36) {
            int k = tid;
            float4 q = quad_p(W, SB + O_X4 + 2 * k, SB + O_R3 + k, 40, f);
            if (bndc) {
                int v = v0 - 2 + k;
                if (v < 0 || v >= t16) q = make_float4(0.f, 0.f, 0.f, 0.f);
            }
            *reinterpret_cast<float4*>(W + O_X3 + 4 * k) = q;
        }
        BAR_LGKM();

        // ---- phase B: 68 x2-quads. quad u = u0-2+k. ----
        if (tid < 68) {
            int k = tid;
            float4 q = quad_p(W, O_X3 + 2 * k, SB + O_R2 + k, 72, f);
            if (bndc) {
                int u = u0 - 2 + k;
                if (u < 0 || u >= t8) q = make_float4(0.f, 0.f, 0.f, 0.f);
            }
            *reinterpret_cast<float4*>(W + O_X2 + 4 * k) = q;
        }
        BAR_LGKM();

        // ---- phase C: 130 x1-quads. quad s = s0-1+l. ----
        float4 myq;
        {
            int l = tid;
            float4 q = quad_p(W, O_X2 + 2 * l + 2, SB + O_R1 + l + 1, 136, f);
            if (bndc) {
                int s = s0 - 1 + l;
                if (s < 0 || s >= t4) q = make_float4(0.f, 0.f, 0.f, 0.f);
            }
            myq = q;
            *reinterpret_cast<float4*>(W + O_X1 + 4 * l) = q;
            if (tid < 2) {
                int l2 = FBLOCK + tid;
                q = quad_p(W, O_X2 + 2 * l2 + 2, SB + O_R1 + l2 + 1, 136, f);
                if (bndc) {
                    int s = s0 - 1 + l2;
                    if (s < 0 || s >= t4) q = make_float4(0.f, 0.f, 0.f, 0.f);
                }
                *reinterpret_cast<float4*>(W + O_X1 + 4 * l2) = q;
            }
        }
        BAR_LGKM();

        // ---- phase D: epilogue. w[d] = x1[n0-4+4*tid+d]; own quad in regs. ----
        float w[12];
        *reinterpret_cast<float4*>(&w[0]) = myq;
        *reinterpret_cast<float4*>(&w[4]) = *reinterpret_cast<const float4*>(W + O_X1 + 4 * (tid + 1));
        *reinterpret_cast<float4*>(&w[8]) = *reinterpret_cast<const float4*>(W + O_X1 + 4 * (tid + 2));

        float rAv[4] = { prc.x, prc.y, prc.z, prc.w };
        float iAv[4] = { pic.x, pic.y, pic.z, pic.w };

        float o[4];
#pragma unroll
        for (int p = 0; p < 4; ++p) {
            float acc = 0.f;
#pragma unroll
            for (int j = 0; j < 7; ++j)          // x1[n+3-j] -> w[p+7-j]
                acc = fmaf(g0r[j], w[p + 7 - j], acc);
#pragma unroll
            for (int j = 0; j < 5; ++j) {        // hi0[n+2-j] -> e = p+4-j
                int e = p + 4 - j;
                float v = (e & 1) ? iAv[e >> 1] : rAv[e >> 1];
                acc = fmaf(g1r[j], v, acc);
            }
            o[p] = acc;
        }
        reinterpret_cast<float4*>(out + (size_t)row * T_)[s0 + tid] =
            make_float4(o[0], o[1], o[2], o[3]);

        // LDS phase barrier before next tile overwrites compute regions is
        // provided by the tile-top barrier (lgkmcnt(0) included there).
        cur ^= 1;
        prc = prn; pic = pin;
    }
}

extern "C" void kernel_launch(void* const* d_in, const int* in_sizes, int n_in,
                              void* d_out, int out_size, void* d_ws, size_t ws_size,
                              hipStream_t stream)
{
    const float* yl = (const float*)d_in[0];
    const float* yhr[8]; const float* yhi[8];
    for (int j = 0; j < 8; ++j) {
        yhr[j] = (const float*)d_in[1 + 2 * j];
        yhi[j] = (const float*)d_in[2 + 2 * j];
    }
    const float* g0o = (const float*)d_in[17];
    const float* g1o = (const float*)d_in[18];
    const float* g0a = (const float*)d_in[19];
    const float* g0b = (const float*)d_in[20];
    const float* g1a = (const float*)d_in[21];
    const float* g1b = (const float*)d_in[22];

    const int BC = 32 * 4;
    const int T_ = 262144;

    // Scratch: final reads x4 while writing the FULL d_out, so x4/x6 live in ws.
    float* x4buf = (float*)d_ws;
    float* x6buf = (float*)((char*)d_ws + ((size_t)32 << 20));

    // K76: yl + yh7 + yh6 -> x6 (L = 8192)
    {
        dim3 grid(8192 / 1024, BC);
        pair_lvl<<<grid, PBLOCK, 0, stream>>>(
            yl, yhr[7], yhi[7], yhr[6], yhi[6], x6buf,
            g0a, g0b, g1a, g1b, 8192);
    }
    // K54: x6 + yh5 + yh4 -> x4 (L = 32768)
    {
        dim3 grid(32768 / 1024, BC);
        pair_lvl<<<grid, PBLOCK, 0, stream>>>(
            x6buf, yhr[5], yhi[5], yhr[4], yhi[4], x4buf,
            g0a, g0b, g1a, g1b, 32768);
    }
    // final4_db: x4 + yh3..yh0 -> out. 2-wave blocks, 8 tiles/block,
    // double-buffered LDS staging with counted vmcnt.
    dim3 grid((T_ / FT) / TPB, BC);
    final4_db<<<grid, FBLOCK, 0, stream>>>(
        x4buf, yhr[3], yhi[3], yhr[2], yhi[2], yhr[1], yhi[1],
        yhr[0], yhi[0], (float*)d_out,
        g0a, g0b, g1a, g1b, g0o, g1o, T_);
}

// Round 9
// 106.342 us; speedup vs baseline: 1.3620x; 1.3620x over previous
//
#include <hip/hip_runtime.h>

#define PBLOCK 256        // pair_lvl block (unchanged structure)
#define FBLOCK 128        // final kernel block = 2 waves
#define FT 1024           // R21: 8 outputs/thread (2 x1-quads/thread in C)

typedef float v2f __attribute__((ext_vector_type(2)));

static __device__ __forceinline__ float ldz(const float* __restrict__ p, int i, int n) {
    return (i >= 0 && i < n) ? p[i] : 0.f;
}

// Phase barrier WITHOUT vmcnt drain: LDS visibility across waves needs
// lgkmcnt only. Keeps the rA/iA epilogue global loads in flight across
// phases A..C.
#define BAR_LGKM() do { \
    asm volatile("s_waitcnt lgkmcnt(0)" ::: "memory"); \
    __builtin_amdgcn_s_barrier(); \
} while (0)

// Full drain barrier (stage): global_load_lds completions are counted by
// vmcnt, so LDS visibility of the staged data needs vmcnt(0) here.
#define BAR_FULL() do { \
    asm volatile("s_waitcnt vmcnt(0) lgkmcnt(0)" ::: "memory"); \
    __builtin_amdgcn_s_barrier(); \
} while (0)

#define AS1C(p) ((const __attribute__((address_space(1))) unsigned int*)(p))
#define AS3(p)  ((__attribute__((address_space(3))) unsigned int*)(p))

// ---- scalar filter set (pair_lvl only) ----
struct QFilt {
    float b0e[5], b0o[5], a0e[5], a0o[5];
    float b1e[5], b1o[5], a1e[5], a1o[5];
};

static __device__ __forceinline__ QFilt load_qfilt(
    const float* __restrict__ g0a, const float* __restrict__ g0b,
    const float* __restrict__ g1a, const float* __restrict__ g1b) {
    const float S2 = 1.4142135623730951f;
    QFilt f;
#pragma unroll
    for (int i = 0; i < 5; ++i) {
        f.b0e[i] = g0b[8 - 2 * i]; f.b0o[i] = g0b[9 - 2 * i];
        f.a0e[i] = g0a[8 - 2 * i]; f.a0o[i] = g0a[9 - 2 * i];
        f.b1e[i] = S2 * g1b[8 - 2 * i]; f.b1o[i] = S2 * g1b[9 - 2 * i];
        f.a1e[i] = S2 * g1a[8 - 2 * i]; f.a1o[i] = S2 * g1a[9 - 2 * i];
    }
    return f;
}

// ---- packed filter set (final kernel) ----
struct QFiltP {
    v2f f01l[5], f23l[5], f01h[5], f23h[5];
};

static __device__ __forceinline__ QFiltP load_qfiltp(
    const float* __restrict__ g0a, const float* __restrict__ g0b,
    const float* __restrict__ g1a, const float* __restrict__ g1b) {
    const float S2 = 1.4142135623730951f;
    QFiltP f;
#pragma unroll
    for (int i = 0; i < 5; ++i) {
        float b0e = g0b[8 - 2 * i], b0o = g0b[9 - 2 * i];
        float a0e = g0a[8 - 2 * i], a0o = g0a[9 - 2 * i];
        float b1e = S2 * g1b[8 - 2 * i], b1o = S2 * g1b[9 - 2 * i];
        float a1e = S2 * g1a[8 - 2 * i], a1o = S2 * g1a[9 - 2 * i];
        f.f01l[i] = (v2f){b0e, a0e};
        f.f23l[i] = (v2f){b0o, a0o};
        f.f01h[i] = (v2f){b1e, a1e};
        f.f23h[i] = (v2f){b1o, a1o};
    }
    return f;
}

// Packed quad: out[4s..4s+3]. lo window as float2 loads (ds_read_b64),
// r/i pair as two b32 (mergeable to ds_read2_b32, ioff<=255).
static __device__ __forceinline__ float4 quad_p(
    const float* base, int loOff, int riOff, int ioff, const QFiltP& f) {
    v2f y01 = (v2f){0.f, 0.f}, y23 = (v2f){0.f, 0.f};
#pragma unroll
    for (int i = 0; i < 5; ++i) {
        v2f lo2 = *reinterpret_cast<const v2f*>(base + loOff + 2 * i);
        v2f ri;
        ri.x = base[riOff + i];
        ri.y = base[riOff + ioff + i];
        y01 = __builtin_elementwise_fma(lo2, f.f01l[i], y01);
        y23 = __builtin_elementwise_fma(lo2, f.f23l[i], y23);
        y01 = __builtin_elementwise_fma(ri, f.f01h[i], y01);
        y23 = __builtin_elementwise_fma(ri, f.f23h[i], y23);
    }
    return make_float4(y01.x, y01.y, y23.x, y23.y);
}

// Interleaved-window quad (pair_lvl only, unchanged).
static __device__ __forceinline__ float4 quad_i(
    const float* __restrict__ lo_s, int lobase,
    const float* __restrict__ r_s, const float* __restrict__ i_s, int ribase,
    const QFilt& f) {
    float y0 = 0.f, y1 = 0.f, y2 = 0.f, y3 = 0.f;
#pragma unroll
    for (int i = 0; i < 5; ++i) {
        float ve = lo_s[lobase + 2 * i], vo = lo_s[lobase + 2 * i + 1];
        float vr = r_s[ribase + i], vi = i_s[ribase + i];
        y0 = fmaf(ve, f.b0e[i], y0); y2 = fmaf(ve, f.b0o[i], y2);
        y1 = fmaf(vo, f.a0e[i], y1); y3 = fmaf(vo, f.a0o[i], y3);
        y0 = fmaf(vr, f.b1e[i], y0); y2 = fmaf(vr, f.b1o[i], y2);
        y1 = fmaf(vi, f.a1e[i], y1); y3 = fmaf(vi, f.a1o[i], y3);
    }
    return make_float4(y0, y1, y2, y3);
}

static __device__ __forceinline__ float4 quad_d(
    const float* __restrict__ Ae, const float* __restrict__ Ao, int base,
    const float* __restrict__ r_s, const float* __restrict__ i_s, int ribase,
    const QFilt& f) {
    float y0 = 0.f, y1 = 0.f, y2 = 0.f, y3 = 0.f;
#pragma unroll
    for (int i = 0; i < 5; ++i) {
        float ve = Ae[base + i], vo = Ao[base + i];
        float vr = r_s[ribase + i], vi = i_s[ribase + i];
        y0 = fmaf(ve, f.b0e[i], y0); y2 = fmaf(ve, f.b0o[i], y2);
        y1 = fmaf(vo, f.a0e[i], y1); y3 = fmaf(vo, f.a0o[i], y3);
        y0 = fmaf(vr, f.b1e[i], y0); y2 = fmaf(vr, f.b1o[i], y2);
        y1 = fmaf(vi, f.a1e[i], y1); y3 = fmaf(vi, f.a1o[i], y3);
    }
    return make_float4(y0, y1, y2, y3);
}

// TWO fused coarse levels (R11 structure, unchanged — measured near floor).
__global__ void __launch_bounds__(PBLOCK) pair_lvl(
    const float* __restrict__ up,
    const float* __restrict__ ru, const float* __restrict__ iu,
    const float* __restrict__ rl, const float* __restrict__ il,
    float* __restrict__ out,
    const float* __restrict__ g0a, const float* __restrict__ g0b,
    const float* __restrict__ g1a, const float* __restrict__ g1b,
    int L)
{
    __shared__ __align__(16) float upw[272], ruw[140], iuw[140], rlw[264], ilw[264];
    __shared__ __align__(16) float Ae[260], Ao[260];
    int tid = threadIdx.x, bx = blockIdx.x, row = blockIdx.y;
    int lup = L >> 2, lu8 = L >> 3, lql = L >> 2;
    const float* uprow = up + (size_t)row * lup;
    const float* rurow = ru + (size_t)row * lu8;
    const float* iurow = iu + (size_t)row * lu8;
    const float* rlrow = rl + (size_t)row * lql;
    const float* ilrow = il + (size_t)row * lql;
    bool bnd = (bx == 0) || (bx == (int)gridDim.x - 1);
    int S = bx << 8;
    int sAu = (S >> 1) - 1;
    int gu = S - 8;
    int gru = (S >> 1) - 4;
    int grl = S - 4;

    for (int i = tid; i < 270; i += PBLOCK) {
        const float* src; float* dst; int k, gb, len;
        if (i < 68)       { src = uprow; dst = upw; k = i;       gb = gu + 4 * k;  len = lup; }
        else if (i < 103) { src = rurow; dst = ruw; k = i - 68;  gb = gru + 4 * k; len = lu8; }
        else if (i < 138) { src = iurow; dst = iuw; k = i - 103; gb = gru + 4 * k; len = lu8; }
        else if (i < 204) { src = rlrow; dst = rlw; k = i - 138; gb = grl + 4 * k; len = lql; }
        else              { src = ilrow; dst = ilw; k = i - 204; gb = grl + 4 * k; len = lql; }
        float4 v;
        if (!bnd) v = *reinterpret_cast<const float4*>(src + gb);
        else { v.x = ldz(src, gb, len); v.y = ldz(src, gb + 1, len);
               v.z = ldz(src, gb + 2, len); v.w = ldz(src, gb + 3, len); }
        *reinterpret_cast<float4*>(dst + 4 * k) = v;
    }
    __syncthreads();

    QFilt f = load_qfilt(g0a, g0b, g1a, g1b);
    if (tid < 130) {
        float4 q = quad_i(upw, 2 * tid + 2, ruw, iuw, tid + 1, f);
        if (bnd) {
            int sp = sAu + tid;
            if (sp < 0 || sp >= lu8) q = make_float4(0.f, 0.f, 0.f, 0.f);
        }
        Ae[2 * tid] = q.x; Ae[2 * tid + 1] = q.z;
        Ao[2 * tid] = q.y; Ao[2 * tid + 1] = q.w;
    }
    __syncthreads();

    float4 res = quad_d(Ae, Ao, tid, rlw, ilw, tid + 2, f);
    reinterpret_cast<float4*>(out + (size_t)row * L)[S + tid] = res;
}

// ---- R21 final kernel: R19 structure (async stage + lgkm-only barriers +
// packed quads + 2-wave blocks) at 8 outputs/thread (FT=1024, 128T).
// Phase C computes 2 x1-quads per thread (kept in registers -> w[0..7]
// free); phase D reads only 2 neighbor quads. Fixed per-block overhead
// amortizes over 2x outputs; FETCH drops back to ~168 MB.
// Packed LDS map (dword offsets into W; slot i stages to W[4i..4i+3]):
#define O_X4 0      // x4  [148]  slots   0..36
#define O_R3 148    // yh3r [76]  slots  37..55   (i3 at +76)
#define O_I3 224    // yh3i [76]  slots  56..74
#define O_R2 300    // yh2r [140] slots  75..109  (i2 at +140)
#define O_I2 440    // yh2i [140] slots 110..144
#define O_R1 580    // yh1r [264] slots 145..210  (i1 at +264)
#define O_I1 844    // yh1i [264] slots 211..276
#define O_X3 1108   // x3 values [280]
#define O_X2 1388   // x2 values [528]
#define O_X1 1916   // x1 quads  [1032]  (258 float4)
#define W_TOT 2948  // dwords = 11792 B
#define NSLOT 277

static __device__ __forceinline__ void slot_map(
    int i, int v0, int u0, int s0, int t4, int t8, int t16,
    const float* x4row, const float* r3row, const float* i3row,
    const float* r2row, const float* i2row,
    const float* r1row, const float* i1row,
    const float*& src, int& gb, int& len)
{
    if (i < 37)       { src = x4row; int k = i;       gb = 2 * v0 - 8 + 4 * k; len = t8;  }
    else if (i < 56)  { src = r3row; int k = i - 37;  gb = v0 - 4 + 4 * k;     len = t16; }
    else if (i < 75)  { src = i3row; int k = i - 56;  gb = v0 - 4 + 4 * k;     len = t16; }
    else if (i < 110) { src = r2row; int k = i - 75;  gb = u0 - 4 + 4 * k;     len = t8;  }
    else if (i < 145) { src = i2row; int k = i - 110; gb = u0 - 4 + 4 * k;     len = t8;  }
    else if (i < 211) { src = r1row; int k = i - 145; gb = s0 - 4 + 4 * k;     len = t4;  }
    else              { src = i1row; int k = i - 211; gb = s0 - 4 + 4 * k;     len = t4;  }
}

__global__ void __launch_bounds__(FBLOCK) final4_async(
    const float* __restrict__ x4,                                 // T/8 per row
    const float* __restrict__ r3, const float* __restrict__ i3,   // T/16 per row
    const float* __restrict__ r2, const float* __restrict__ i2,   // T/8 per row
    const float* __restrict__ r1, const float* __restrict__ i1,   // T/4 per row
    const float* __restrict__ r0, const float* __restrict__ i0,   // T/2 per row
    float* __restrict__ out,                                      // T per row
    const float* __restrict__ g0a, const float* __restrict__ g0b,
    const float* __restrict__ g1a, const float* __restrict__ g1b,
    const float* __restrict__ g0o, const float* __restrict__ g1o,
    int T_)
{
    const float S2 = 1.4142135623730951f;
    __shared__ __align__(16) float W[W_TOT];

    int row = blockIdx.y, tid = threadIdx.x, bx = blockIdx.x;
    int t2 = T_ >> 1, t4 = T_ >> 2, t8 = T_ >> 3, t16 = T_ >> 4;
    int s0 = bx << 8, u0 = bx << 7, v0 = bx << 6, h0 = bx << 9;
    const float* x4row = x4 + (size_t)row * t8;
    const float* r3row = r3 + (size_t)row * t16;
    const float* i3row = i3 + (size_t)row * t16;
    const float* r2row = r2 + (size_t)row * t8;
    const float* i2row = i2 + (size_t)row * t8;
    const float* r1row = r1 + (size_t)row * t4;
    const float* i1row = i1 + (size_t)row * t4;
    const float* r0row = r0 + (size_t)row * t2;
    const float* i0row = i0 + (size_t)row * t2;
    bool bnd = (bx == 0) || (bx == (int)gridDim.x - 1);

    // ---- stage: 277 float4 slots, direct HBM -> LDS (wave-linear dest) ----
    if (!bnd) {
#pragma unroll
        for (int it = 0; it < 2; ++it) {
            int i = tid + FBLOCK * it;
            const float* src; int gb, len;
            slot_map(i, v0, u0, s0, t4, t8, t16,
                     x4row, r3row, i3row, r2row, i2row, r1row, i1row, src, gb, len);
            __builtin_amdgcn_global_load_lds(AS1C(src + gb), AS3(W + 4 * i), 16, 0, 0);
        }
        if (tid < NSLOT - 2 * FBLOCK) {
            int i = tid + 2 * FBLOCK;
            const float* src; int gb, len;
            slot_map(i, v0, u0, s0, t4, t8, t16,
                     x4row, r3row, i3row, r2row, i2row, r1row, i1row, src, gb, len);
            __builtin_amdgcn_global_load_lds(AS1C(src + gb), AS3(W + 4 * i), 16, 0, 0);
        }
    } else {
#pragma unroll
        for (int it = 0; it < 3; ++it) {
            int i = tid + FBLOCK * it;
            if (i < NSLOT) {
                const float* src; int gb, len;
                slot_map(i, v0, u0, s0, t4, t8, t16,
                         x4row, r3row, i3row, r2row, i2row, r1row, i1row, src, gb, len);
                float4 v;
                v.x = ldz(src, gb, len);     v.y = ldz(src, gb + 1, len);
                v.z = ldz(src, gb + 2, len); v.w = ldz(src, gb + 3, len);
                *reinterpret_cast<float4*>(W + 4 * i) = v;
            }
        }
    }
    BAR_FULL();   // staged LDS data visible; nothing else in flight yet

    // ---- epilogue loads issued NOW: stay in flight under phases A..C ----
    // rA[e] = r0[h0 + 4*tid - 1 + e], e = 0..5 (8 outputs need 6-wide window)
    float rA[6], iA[6];
    {
        int u0e = h0 + 4 * tid - 1;
        if (!bnd) {
            float4 va = *reinterpret_cast<const float4*>(r0row + u0e);
            float2 va2 = *reinterpret_cast<const float2*>(r0row + u0e + 4);
            float4 vb = *reinterpret_cast<const float4*>(i0row + u0e);
            float2 vb2 = *reinterpret_cast<const float2*>(i0row + u0e + 4);
            rA[0] = va.x; rA[1] = va.y; rA[2] = va.z; rA[3] = va.w;
            rA[4] = va2.x; rA[5] = va2.y;
            iA[0] = vb.x; iA[1] = vb.y; iA[2] = vb.z; iA[3] = vb.w;
            iA[4] = vb2.x; iA[5] = vb2.y;
        } else {
#pragma unroll
            for (int e = 0; e < 6; ++e) {
                rA[e] = ldz(r0row, u0e + e, t2);
                iA[e] = ldz(i0row, u0e + e, t2);
            }
        }
    }

    QFiltP f = load_qfiltp(g0a, g0b, g1a, g1b);
    float g0r[7], g1r[5];
#pragma unroll
    for (int j = 0; j < 7; ++j) g0r[j] = g0o[j];
#pragma unroll
    for (int j = 0; j < 5; ++j) g1r[j] = S2 * g1o[j];

    // ---- phase A: 69 x3-quads. quad v = v0-2+k. ----
    if (tid < 69) {
        int k = tid;
        float4 q = quad_p(W, O_X4 + 2 * k, O_R3 + k, 76, f);
        if (bnd) {
            int v = v0 - 2 + k;
            if (v < 0 || v >= t16) q = make_float4(0.f, 0.f, 0.f, 0.f);
        }
        *reinterpret_cast<float4*>(W + O_X3 + 4 * k) = q;
    }
    BAR_LGKM();

    // ---- phase B: 132 x2-quads. quad u = u0-2+k; k = tid and tid+128 (<4). ----
    {
        int k = tid;
        float4 q = quad_p(W, O_X3 + 2 * k, O_R2 + k, 140, f);
        if (bnd) {
            int u = u0 - 2 + k;
            if (u < 0 || u >= t8) q = make_float4(0.f, 0.f, 0.f, 0.f);
        }
        *reinterpret_cast<float4*>(W + O_X2 + 4 * k) = q;
        if (tid < 4) {
            int k2 = tid + FBLOCK;
            q = quad_p(W, O_X3 + 2 * k2, O_R2 + k2, 140, f);
            if (bnd) {
                int u = u0 - 2 + k2;
                if (u < 0 || u >= t8) q = make_float4(0.f, 0.f, 0.f, 0.f);
            }
            *reinterpret_cast<float4*>(W + O_X2 + 4 * k2) = q;
        }
    }
    BAR_LGKM();

    // ---- phase C: 258 x1-quads, 2 per thread (l = 2t, 2t+1; s = s0-1+l),
    // both kept in registers; extras l = 256,257 by tid < 2. ----
    float4 mq0, mq1;
    {
        int l = 2 * tid;
        mq0 = quad_p(W, O_X2 + 2 * l + 2, O_R1 + l + 1, 264, f);
        mq1 = quad_p(W, O_X2 + 2 * l + 4, O_R1 + l + 2, 264, f);
        if (bnd) {
            int s = s0 - 1 + l;
            if (s < 0 || s >= t4)         mq0 = make_float4(0.f, 0.f, 0.f, 0.f);
            if (s + 1 < 0 || s + 1 >= t4) mq1 = make_float4(0.f, 0.f, 0.f, 0.f);
        }
        *reinterpret_cast<float4*>(W + O_X1 + 4 * l) = mq0;
        *reinterpret_cast<float4*>(W + O_X1 + 4 * (l + 1)) = mq1;
        if (tid < 2) {
            int l2 = 256 + tid;
            float4 q = quad_p(W, O_X2 + 2 * l2 + 2, O_R1 + l2 + 1, 264, f);
            if (bnd) {
                int s = s0 - 1 + l2;
                if (s < 0 || s >= t4) q = make_float4(0.f, 0.f, 0.f, 0.f);
            }
            *reinterpret_cast<float4*>(W + O_X1 + 4 * l2) = q;
        }
    }
    BAR_LGKM();

    // ---- phase D: 8 outputs. w[d] = x1[n0-4+8*tid+d] (quads 2t..2t+3). ----
    float w[16];
    *reinterpret_cast<float4*>(&w[0])  = mq0;    // own, no LDS read
    *reinterpret_cast<float4*>(&w[4])  = mq1;
    *reinterpret_cast<float4*>(&w[8])  = *reinterpret_cast<const float4*>(W + O_X1 + 4 * (2 * tid + 2));
    *reinterpret_cast<float4*>(&w[12]) = *reinterpret_cast<const float4*>(W + O_X1 + 4 * (2 * tid + 3));

    float o[8];
#pragma unroll
    for (int p = 0; p < 8; ++p) {
        float acc = 0.f;
#pragma unroll
        for (int j = 0; j < 7; ++j)          // x1[n+3-j] -> w[p+7-j]
            acc = fmaf(g0r[j], w[p + 7 - j], acc);
#pragma unroll
        for (int j = 0; j < 5; ++j) {        // hi0[n+2-j] -> e = p+4-j
            int e = p + 4 - j;
            float v = (e & 1) ? iA[e >> 1] : rA[e >> 1];
            acc = fmaf(g1r[j], v, acc);
        }
        o[p] = acc;
    }
    float4* op = reinterpret_cast<float4*>(out + (size_t)row * T_) + s0 + 2 * tid;
    op[0] = make_float4(o[0], o[1], o[2], o[3]);
    op[1] = make_float4(o[4], o[5], o[6], o[7]);
}

extern "C" void kernel_launch(void* const* d_in, const int* in_sizes, int n_in,
                              void* d_out, int out_size, void* d_ws, size_t ws_size,
                              hipStream_t stream)
{
    const float* yl = (const float*)d_in[0];
    const float* yhr[8]; const float* yhi[8];
    for (int j = 0; j < 8; ++j) {
        yhr[j] = (const float*)d_in[1 + 2 * j];
        yhi[j] = (const float*)d_in[2 + 2 * j];
    }
    const float* g0o = (const float*)d_in[17];
    const float* g1o = (const float*)d_in[18];
    const float* g0a = (const float*)d_in[19];
    const float* g0b = (const float*)d_in[20];
    const float* g1a = (const float*)d_in[21];
    const float* g1b = (const float*)d_in[22];

    const int BC = 32 * 4;
    const int T_ = 262144;

    // Scratch: final reads x4 while writing the FULL d_out, so x4/x6 live in ws.
    float* x4buf = (float*)d_ws;
    float* x6buf = (float*)((char*)d_ws + ((size_t)32 << 20));

    // K76: yl + yh7 + yh6 -> x6 (L = 8192)
    {
        dim3 grid(8192 / 1024, BC);
        pair_lvl<<<grid, PBLOCK, 0, stream>>>(
            yl, yhr[7], yhi[7], yhr[6], yhi[6], x6buf,
            g0a, g0b, g1a, g1b, 8192);
    }
    // K54: x6 + yh5 + yh4 -> x4 (L = 32768)
    {
        dim3 grid(32768 / 1024, BC);
        pair_lvl<<<grid, PBLOCK, 0, stream>>>(
            x6buf, yhr[5], yhi[5], yhr[4], yhi[4], x4buf,
            g0a, g0b, g1a, g1b, 32768);
    }
    // final4_async: x4 + yh3..yh0 -> out. FT=1024, 128T, 8 outputs/thread.
    dim3 grid(T_ / FT, BC);
    final4_async<<<grid, FBLOCK, 0, stream>>>(
        x4buf, yhr[3], yhi[3], yhr[2], yhi[2], yhr[1], yhi[1],
        yhr[0], yhi[0], (float*)d_out,
        g0a, g0b, g1a, g1b, g0o, g1o, T_);
}